// Round 7
// baseline (985.470 us; speedup 1.0000x reference)
//
#include <hip/hip_runtime.h>
#include <hip/hip_bf16.h>

// B=128, T=512, E=128, H=128, 4H=512, HD=256, K=17, V=30000
// M = T*B = 65536 rows, m = t*128 + b

typedef __attribute__((ext_vector_type(8))) short short8;   // 8 bf16 in 4 VGPRs
typedef __attribute__((ext_vector_type(4))) float f32x4;
typedef __fp16 h2 __attribute__((ext_vector_type(2)));      // packed 2xf16 (matches cvt_pkrtz/fdot2)

__device__ __forceinline__ float bf2f(unsigned short u) {
    return __uint_as_float(((unsigned int)u) << 16);
}
__device__ __forceinline__ unsigned short f2bf(float f) {
    unsigned int x = __float_as_uint(f);
    x += 0x7FFFu + ((x >> 16) & 1u);   // round to nearest even
    return (unsigned short)(x >> 16);
}
__device__ __forceinline__ float sigf(float x) {
    return __builtin_amdgcn_rcpf(1.f + __expf(-x));
}
__device__ __forceinline__ float tanhf_(float x) {
    float e = __expf(-2.f * fabsf(x));
    float t = (1.f - e) * __builtin_amdgcn_rcpf(1.f + e);
    return copysignf(t, x);
}
__device__ __forceinline__ h2 i2h2(int x) { h2 r; __builtin_memcpy(&r, &x, 4); return r; }
__device__ __forceinline__ int h22i(h2 x) { int r; __builtin_memcpy(&r, &x, 4); return r; }

__device__ __forceinline__ float dot2acc(h2 a, h2 b, float c) {
#if __has_builtin(__builtin_amdgcn_fdot2)
    return __builtin_amdgcn_fdot2(a, b, c, false);
#else
    return fmaf((float)a.x, (float)b.x, fmaf((float)a.y, (float)b.y, c));
#endif
}

// ---------------------------------------------------------------------------
// Kernel 1: xp[dir][m][512] (bf16) = embed[ids] @ w_ih^T + b_ih + b_hh
// Grid 512 (one per t), 256 threads. MFMA bf16 16x16x32.
// Epilogue via LDS transpose -> coalesced 16B stores.
// Backward direction rows are stored time-reversed: xp_b[511-t][b][:].
// ---------------------------------------------------------------------------
__global__ __launch_bounds__(256) void xp_gemm(
    const int* __restrict__ ids, const float* __restrict__ emb,
    const float* __restrict__ w_ih_f, const float* __restrict__ w_ih_b,
    const float* __restrict__ b_ih_f, const float* __restrict__ b_hh_f,
    const float* __restrict__ b_ih_b, const float* __restrict__ b_hh_b,
    unsigned short* __restrict__ xp)
{
    __shared__ unsigned short Ab[128][136];   // 16B-aligned rows (272B stride)
    __shared__ unsigned short Wb[64][136];
    __shared__ unsigned short Cb[128][72];    // C-tile transpose buffer (144B stride)

    const int tid = threadIdx.x;
    const int m0  = blockIdx.x * 128;
    const int t   = m0 >> 7;                  // fixed timestep for this tile

    // stage A: 2 threads per row, 64 floats each, f32 -> bf16
    {
        const int r = tid >> 1, half = tid & 1;
        const int id = ids[r * 512 + t];      // b = r
        const float4* src = (const float4*)(emb + (long)id * 128 + half * 64);
        #pragma unroll
        for (int j = 0; j < 16; ++j) {
            float4 v = src[j];
            unsigned int p0 = (unsigned int)f2bf(v.x) | ((unsigned int)f2bf(v.y) << 16);
            unsigned int p1 = (unsigned int)f2bf(v.z) | ((unsigned int)f2bf(v.w) << 16);
            *(unsigned int*)&Ab[r][half*64 + j*4]     = p0;
            *(unsigned int*)&Ab[r][half*64 + j*4 + 2] = p1;
        }
    }

    const int w  = tid >> 6, l = tid & 63;
    const int lr = l & 15,  lg = l >> 4;

    for (int it = 0; it < 16; ++it) {
        const int n0 = it * 64;
        __syncthreads();   // Wb/Cb safe to overwrite (prior readers done)
        {   // stage W: 4 threads per row, 32 floats each
            const int r = tid >> 2, q = tid & 3;
            const int g = n0 + r;
            const float* srcw = (g < 512) ? (w_ih_f + (long)g * 128)
                                          : (w_ih_b + (long)(g - 512) * 128);
            const float4* s4 = (const float4*)(srcw + q * 32);
            #pragma unroll
            for (int j = 0; j < 8; ++j) {
                float4 v = s4[j];
                unsigned int p0 = (unsigned int)f2bf(v.x) | ((unsigned int)f2bf(v.y) << 16);
                unsigned int p1 = (unsigned int)f2bf(v.z) | ((unsigned int)f2bf(v.w) << 16);
                *(unsigned int*)&Wb[r][q*32 + j*4]     = p0;
                *(unsigned int*)&Wb[r][q*32 + j*4 + 2] = p1;
            }
        }
        __syncthreads();

        f32x4 acc[2][4];
        #pragma unroll
        for (int a = 0; a < 2; ++a)
            #pragma unroll
            for (int c = 0; c < 4; ++c)
                acc[a][c] = (f32x4){0.f, 0.f, 0.f, 0.f};

        #pragma unroll
        for (int kk = 0; kk < 4; ++kk) {
            const int kb = kk * 32 + lg * 8;   // consistent A/B k-mapping
            short8 af[2], bfr[4];
            #pragma unroll
            for (int mt2 = 0; mt2 < 2; ++mt2)
                af[mt2] = *(const short8*)&Ab[w*32 + mt2*16 + lr][kb];
            #pragma unroll
            for (int nt2 = 0; nt2 < 4; ++nt2)
                bfr[nt2] = *(const short8*)&Wb[nt2*16 + lr][kb];
            #pragma unroll
            for (int mt2 = 0; mt2 < 2; ++mt2)
                #pragma unroll
                for (int nt2 = 0; nt2 < 4; ++nt2)
                    acc[mt2][nt2] = __builtin_amdgcn_mfma_f32_16x16x32_bf16(
                        af[mt2], bfr[nt2], acc[mt2][nt2], 0, 0, 0);
        }

        // write C fragments (+bias) into LDS transpose buffer
        #pragma unroll
        for (int nt2 = 0; nt2 < 4; ++nt2) {
            const int gc = n0 + nt2*16 + lr;
            const float bv = (gc < 512) ? (b_ih_f[gc] + b_hh_f[gc])
                                        : (b_ih_b[gc-512] + b_hh_b[gc-512]);
            #pragma unroll
            for (int mt2 = 0; mt2 < 2; ++mt2) {
                #pragma unroll
                for (int r = 0; r < 4; ++r) {
                    const int lrow = w*32 + mt2*16 + lg*4 + r;   // 0..127
                    Cb[lrow][nt2*16 + lr] = f2bf(acc[mt2][nt2][r] + bv);
                }
            }
        }
        __syncthreads();

        // coalesced store: thread (rr,hf) stores 32 bf16 = 4 x 16B
        {
            const int rr = tid >> 1, hf = tid & 1;
            const int grow = m0 + rr;
            long dst;
            if (n0 < 512) {
                dst = (long)grow * 512 + n0 + hf*32;
            } else {
                const int tt = grow >> 7, bb = grow & 127;
                dst = 33554432L + (long)((511 - tt) * 128 + bb) * 512 + (n0 - 512) + hf*32;
            }
            const unsigned short* srcC = &Cb[rr][hf*32];
            unsigned short* dp = xp + dst;
            #pragma unroll
            for (int j = 0; j < 4; ++j)
                *(short8*)(dp + j*8) = *(const short8*)(srcC + j*8);
        }
    }
}

// ---------------------------------------------------------------------------
// Kernel 2: LSTM recurrence. Grid 128 blocks x 512 threads; each block runs
// TWO independent (dir,b) sequences (threads 0-255 = seq0, 256-511 = seq1),
// giving 8 waves/CU = 2 waves/SIMD so one wave's readlane/LDS stalls are
// hidden by the other. __launch_bounds__(512,2) caps VGPRs at 256 so the
// 128 weight regs fit. One __syncthreads per step via parity-double-buffered
// gate LDS.
// ---------------------------------------------------------------------------
__global__ __launch_bounds__(512, 2) void lstm_rec(
    const unsigned short* __restrict__ xp,
    const float* __restrict__ w_hh_f, const float* __restrict__ w_hh_b,
    unsigned short* __restrict__ hbuf)
{
    const int tid  = threadIdx.x;
    const int s    = tid >> 8;          // sequence slot within block (0/1)
    const int stid = tid & 255;         // thread id within sequence
    const int seq  = blockIdx.x * 2 + s;
    const int dir  = seq >> 7, b = seq & 127;
    const float* whh = dir ? w_hh_b : w_hh_f;

    // pack weight rows stid and stid+256 into f16 pairs (64+64 VGPRs)
    h2 w1p[64], w2p[64];
    #pragma unroll
    for (int j = 0; j < 16; ++j) {
        float4 a = *(const float4*)(whh + (long)stid * 128 + j*8);
        float4 c = *(const float4*)(whh + (long)stid * 128 + j*8 + 4);
        w1p[j*4+0] = __builtin_amdgcn_cvt_pkrtz(a.x, a.y);
        w1p[j*4+1] = __builtin_amdgcn_cvt_pkrtz(a.z, a.w);
        w1p[j*4+2] = __builtin_amdgcn_cvt_pkrtz(c.x, c.y);
        w1p[j*4+3] = __builtin_amdgcn_cvt_pkrtz(c.z, c.w);
    }
    #pragma unroll
    for (int j = 0; j < 16; ++j) {
        float4 a = *(const float4*)(whh + (long)(stid + 256) * 128 + j*8);
        float4 c = *(const float4*)(whh + (long)(stid + 256) * 128 + j*8 + 4);
        w2p[j*4+0] = __builtin_amdgcn_cvt_pkrtz(a.x, a.y);
        w2p[j*4+1] = __builtin_amdgcn_cvt_pkrtz(a.z, a.w);
        w2p[j*4+2] = __builtin_amdgcn_cvt_pkrtz(c.x, c.y);
        w2p[j*4+3] = __builtin_amdgcn_cvt_pkrtz(c.z, c.w);
    }

    // parity-double-buffered gate preactivations: [seq][parity][gate][unit]
    __shared__ float gl[2][2][4][128];
    const int l   = stid & 63;
    const int u   = stid & 127;
    const int grp = stid >> 7;     // 0 -> writes i,g ; 1 -> writes f,o

    int hpi = 0;                   // packed f16 pair (h[2l], h[2l+1]), per-wave copy
    float cv0 = 0.f, cv1 = 0.f;    // c[2l], c[2l+1]
    const unsigned short* xpd = xp + (long)dir * 33554432L;

    // prefetch step 0's xp row
    unsigned short nxa = xpd[((long)0 * 128 + b) * 512 + stid];
    unsigned short nxb = xpd[((long)0 * 128 + b) * 512 + stid + 256];

    for (int t = 0; t < 512; ++t) {
        const int p = t & 1;
        const float xpv1 = bf2f(nxa);
        const float xpv2 = bf2f(nxb);
        if (t < 511) {   // prefetch next step (covered by the dot loop below)
            const unsigned short* nr = xpd + ((long)(t+1) * 128 + b) * 512;
            nxa = nr[stid];
            nxb = nr[stid + 256];
        }

        float acc1 = 0.f, acc2 = 0.f;
        #pragma unroll
        for (int j = 0; j < 64; ++j) {
            const h2 hj = i2h2(__builtin_amdgcn_readlane(hpi, j));
            acc1 = dot2acc(w1p[j], hj, acc1);
            acc2 = dot2acc(w2p[j], hj, acc2);
        }

        gl[s][p][grp][u]     = acc1 + xpv1;
        gl[s][p][2 + grp][u] = acc2 + xpv2;
        __syncthreads();   // gates of buf p complete; buf p^1 was last read
                           // before the PREVIOUS sync, so next step's writes
                           // to it are safe without a second barrier.

        const float2 iv = *(const float2*)&gl[s][p][0][2*l];
        const float2 fv = *(const float2*)&gl[s][p][1][2*l];
        const float2 gv = *(const float2*)&gl[s][p][2][2*l];
        const float2 ov = *(const float2*)&gl[s][p][3][2*l];
        cv0 = sigf(fv.x) * cv0 + sigf(iv.x) * tanhf_(gv.x);
        cv1 = sigf(fv.y) * cv1 + sigf(iv.y) * tanhf_(gv.y);
        const float h0 = sigf(ov.x) * tanhf_(cv0);
        const float h1 = sigf(ov.y) * tanhf_(cv1);
        hpi = h22i(__builtin_amdgcn_cvt_pkrtz(h0, h1));

        if (stid < 64) {   // first wave of each sequence stores h
            const int tt = dir ? (511 - t) : t;
            unsigned short* hd = hbuf + ((long)b * 512 + tt) * 256 + dir * 128;
            *(unsigned int*)&hd[2*l] =
                (unsigned int)f2bf(h0) | ((unsigned int)f2bf(h1) << 16);
        }
    }
}

// ---------------------------------------------------------------------------
// Kernel 3: emissions via MFMA. M=128 rows/block (grid 512), N=32 (17 used),
// K=256. w_emit staged in zero-padded bf16 fragments, h read direct global.
// ---------------------------------------------------------------------------
__global__ __launch_bounds__(256) void emission(
    const unsigned short* __restrict__ hbuf, const float* __restrict__ w_emit,
    const float* __restrict__ b_emit, float* __restrict__ em)
{
    const int tid = threadIdx.x, w = tid >> 6, l = tid & 63;
    const int lr = l & 15, lg = l >> 4;
    const int m0 = blockIdx.x * 128;

    // B fragments: 2 n-tiles x 8 k-frags, cols >= 17 zero
    short8 bf[2][8];
    #pragma unroll
    for (int nt = 0; nt < 2; ++nt) {
        const int col = nt*16 + lr;
        #pragma unroll
        for (int kk = 0; kk < 8; ++kk) {
            short8 v = (short8){0,0,0,0,0,0,0,0};
            if (col < 17) {
                const float* s = w_emit + (long)col * 256 + kk*32 + lg*8;
                const float4 a = *(const float4*)s;
                const float4 c = *(const float4*)(s + 4);
                v[0] = (short)f2bf(a.x); v[1] = (short)f2bf(a.y);
                v[2] = (short)f2bf(a.z); v[3] = (short)f2bf(a.w);
                v[4] = (short)f2bf(c.x); v[5] = (short)f2bf(c.y);
                v[6] = (short)f2bf(c.z); v[7] = (short)f2bf(c.w);
            }
            bf[nt][kk] = v;
        }
    }

    f32x4 acc[2][2];
    #pragma unroll
    for (int a = 0; a < 2; ++a)
        #pragma unroll
        for (int c = 0; c < 2; ++c)
            acc[a][c] = (f32x4){0.f, 0.f, 0.f, 0.f};

    #pragma unroll
    for (int kk = 0; kk < 8; ++kk) {
        short8 af[2];
        #pragma unroll
        for (int mt = 0; mt < 2; ++mt) {
            const long row = m0 + w*32 + mt*16 + lr;
            af[mt] = *(const short8*)(hbuf + row * 256 + kk*32 + lg*8);
        }
        #pragma unroll
        for (int mt = 0; mt < 2; ++mt)
            #pragma unroll
            for (int nt = 0; nt < 2; ++nt)
                acc[mt][nt] = __builtin_amdgcn_mfma_f32_16x16x32_bf16(
                    af[mt], bf[nt][kk], acc[mt][nt], 0, 0, 0);
    }

    #pragma unroll
    for (int mt = 0; mt < 2; ++mt)
        #pragma unroll
        for (int nt = 0; nt < 2; ++nt) {
            const int col = nt*16 + lr;
            if (col < 17) {
                const float bb = b_emit[col];
                #pragma unroll
                for (int r = 0; r < 4; ++r) {
                    const long row = m0 + w*32 + mt*16 + lg*4 + r;
                    em[row * 17 + col] = acc[mt][nt][r] + bb;
                }
            }
        }
}

// ---------------------------------------------------------------------------
// Kernel 4: CRF per batch element. Linear-domain forward, renorm every 4
// steps (worst-case growth e^76 < f32 max).
// ---------------------------------------------------------------------------
__global__ __launch_bounds__(64) void crf(
    const float* __restrict__ em, const int* __restrict__ tags,
    const float* __restrict__ start_t, const float* __restrict__ end_t,
    const float* __restrict__ trans, float* __restrict__ llh)
{
    const int b = blockIdx.x, l = threadIdx.x;
    const int* tg = tags + b * 512;
    const float* emb_ = em + (long)b * 512 * 17;

    // ---- numerator (gold path score), all 64 lanes ----
    float sc = 0.f;
    #pragma unroll
    for (int it = 0; it < 8; ++it) {
        const int t = it * 64 + l;
        const int cur = tg[t];
        float e = emb_[t * 17 + cur];
        float tr = (t > 0) ? trans[tg[t-1] * 17 + cur] : 0.f;
        sc += e + tr;
    }
    #pragma unroll
    for (int m = 32; m >= 1; m >>= 1) sc += __shfl_xor(sc, m, 64);

    // ---- denominator: linear-domain forward, periodic renorm ----
    const bool act = (l < 17);
    const int j = act ? l : 16;

    float eT[17];
    #pragma unroll
    for (int i = 0; i < 17; ++i) eT[i] = __expf(trans[i * 17 + j]);

    float v0 = act ? (start_t[j] + emb_[j]) : -1e30f;
    float m0 = v0;
    #pragma unroll
    for (int m = 32; m >= 1; m >>= 1) m0 = fmaxf(m0, __shfl_xor(m0, m, 64));
    float al = act ? __expf(v0 - m0) : 0.f;
    float accl = m0;   // accumulated natural-log scale

    float em_next = emb_[17 + j];
    for (int t = 1; t < 512; ++t) {
        const float emv = em_next;
        if (t + 1 < 512) em_next = emb_[(t + 1) * 17 + j];
        float s = 0.f;
        #pragma unroll
        for (int i = 0; i < 17; ++i) {
            const float ai = __int_as_float(
                __builtin_amdgcn_readlane(__float_as_int(al), i));
            s = fmaf(ai, eT[i], s);
        }
        al = act ? s * __expf(emv) : 0.f;
        if ((t & 3) == 0) {   // renorm every 4 steps
            float mx = al;
            #pragma unroll
            for (int m = 32; m >= 1; m >>= 1) mx = fmaxf(mx, __shfl_xor(mx, m, 64));
            al = al * __builtin_amdgcn_rcpf(mx);
            accl += __logf(mx);
        }
    }
    float fin = act ? al * __expf(end_t[j]) : 0.f;
    #pragma unroll
    for (int m = 32; m >= 1; m >>= 1) fin += __shfl_xor(fin, m, 64);
    const float logZ = __logf(fin) + accl;

    if (l == 0) {
        sc += start_t[tg[0]] + end_t[tg[511]];
        llh[b] = sc - logZ;
    }
}

// ---------------------------------------------------------------------------
// Kernel 5: nll = -mean(llh)
// ---------------------------------------------------------------------------
__global__ __launch_bounds__(64) void finalize(
    const float* __restrict__ llh, float* __restrict__ out)
{
    const int l = threadIdx.x;
    float s = llh[l] + llh[l + 64];
    #pragma unroll
    for (int m = 32; m >= 1; m >>= 1) s += __shfl_xor(s, m, 64);
    if (l == 0) out[0] = -s * (1.f / 128.f);
}

// ---------------------------------------------------------------------------
extern "C" void kernel_launch(void* const* d_in, const int* in_sizes, int n_in,
                              void* d_out, int out_size, void* d_ws, size_t ws_size,
                              hipStream_t stream) {
    (void)in_sizes; (void)n_in; (void)out_size; (void)ws_size;
    const int*   ids    = (const int*)d_in[0];
    const int*   tags   = (const int*)d_in[1];
    // d_in[2] = mask: all-ones by construction, ignored
    const float* emb    = (const float*)d_in[3];
    const float* w_ih_f = (const float*)d_in[4];
    const float* w_hh_f = (const float*)d_in[5];
    const float* b_ih_f = (const float*)d_in[6];
    const float* b_hh_f = (const float*)d_in[7];
    const float* w_ih_b = (const float*)d_in[8];
    const float* w_hh_b = (const float*)d_in[9];
    const float* b_ih_b = (const float*)d_in[10];
    const float* b_hh_b = (const float*)d_in[11];
    const float* w_emit = (const float*)d_in[12];
    const float* b_emit = (const float*)d_in[13];
    const float* st     = (const float*)d_in[14];
    const float* en     = (const float*)d_in[15];
    const float* tr     = (const float*)d_in[16];

    char* ws = (char*)d_ws;
    unsigned short* xp   = (unsigned short*)(ws);                 // bf16 [2][65536][512] = 128 MiB
    unsigned short* hbuf = (unsigned short*)(ws + 134217728L);    // bf16 [128][512][256] = 32 MiB
    float*          em   = (float*)(ws + 167772160L);             // f32  [65536][17]
    float*          llh  = (float*)(ws + 172228608L);             // f32  [128]
    float*          out  = (float*)d_out;

    xp_gemm<<<dim3(512), dim3(256), 0, stream>>>(ids, emb, w_ih_f, w_ih_b,
                                                 b_ih_f, b_hh_f, b_ih_b, b_hh_b, xp);
    lstm_rec<<<dim3(128), dim3(512), 0, stream>>>(xp, w_hh_f, w_hh_b, hbuf);
    emission<<<dim3(512), dim3(256), 0, stream>>>(hbuf, w_emit, b_emit, em);
    crf<<<dim3(128), dim3(64), 0, stream>>>(em, tags, st, en, tr, llh);
    finalize<<<dim3(1), dim3(64), 0, stream>>>(llh, out);
}

// Round 8
// 729.753 us; speedup vs baseline: 1.3504x; 1.3504x over previous
//
#include <hip/hip_runtime.h>
#include <hip/hip_bf16.h>

// B=128, T=512, E=128, H=128, 4H=512, HD=256, K=17, V=30000
// M = T*B = 65536 rows, m = t*128 + b

typedef __attribute__((ext_vector_type(8))) short short8;   // 8 bf16 in 4 VGPRs
typedef __attribute__((ext_vector_type(4))) float f32x4;
typedef __fp16 h2 __attribute__((ext_vector_type(2)));      // packed 2xf16 (matches cvt_pkrtz/fdot2)

__device__ __forceinline__ float bf2f(unsigned short u) {
    return __uint_as_float(((unsigned int)u) << 16);
}
__device__ __forceinline__ unsigned short f2bf(float f) {
    unsigned int x = __float_as_uint(f);
    x += 0x7FFFu + ((x >> 16) & 1u);   // round to nearest even
    return (unsigned short)(x >> 16);
}
__device__ __forceinline__ float sigf(float x) {
    return __builtin_amdgcn_rcpf(1.f + __expf(-x));
}
__device__ __forceinline__ float tanhf_(float x) {
    float e = __expf(-2.f * fabsf(x));
    float t = (1.f - e) * __builtin_amdgcn_rcpf(1.f + e);
    return copysignf(t, x);
}
__device__ __forceinline__ h2 i2h2(int x) { h2 r; __builtin_memcpy(&r, &x, 4); return r; }
__device__ __forceinline__ int h22i(h2 x) { int r; __builtin_memcpy(&r, &x, 4); return r; }

__device__ __forceinline__ float dot2acc(h2 a, h2 b, float c) {
#if __has_builtin(__builtin_amdgcn_fdot2)
    return __builtin_amdgcn_fdot2(a, b, c, false);
#else
    return fmaf((float)a.x, (float)b.x, fmaf((float)a.y, (float)b.y, c));
#endif
}

// ---------------------------------------------------------------------------
// Kernel 1: xp[dir][m][512] (bf16) = embed[ids] @ w_ih^T + b_ih + b_hh
// Grid 512 (one per t), 256 threads. MFMA bf16 16x16x32.
// Epilogue via LDS transpose -> coalesced 16B stores.
// Backward direction rows are stored time-reversed: xp_b[511-t][b][:].
// ---------------------------------------------------------------------------
__global__ __launch_bounds__(256) void xp_gemm(
    const int* __restrict__ ids, const float* __restrict__ emb,
    const float* __restrict__ w_ih_f, const float* __restrict__ w_ih_b,
    const float* __restrict__ b_ih_f, const float* __restrict__ b_hh_f,
    const float* __restrict__ b_ih_b, const float* __restrict__ b_hh_b,
    unsigned short* __restrict__ xp)
{
    __shared__ unsigned short Ab[128][136];   // 16B-aligned rows (272B stride)
    __shared__ unsigned short Wb[64][136];
    __shared__ unsigned short Cb[128][72];    // C-tile transpose buffer (144B stride)

    const int tid = threadIdx.x;
    const int m0  = blockIdx.x * 128;
    const int t   = m0 >> 7;                  // fixed timestep for this tile

    // stage A: 2 threads per row, 64 floats each, f32 -> bf16
    {
        const int r = tid >> 1, half = tid & 1;
        const int id = ids[r * 512 + t];      // b = r
        const float4* src = (const float4*)(emb + (long)id * 128 + half * 64);
        #pragma unroll
        for (int j = 0; j < 16; ++j) {
            float4 v = src[j];
            unsigned int p0 = (unsigned int)f2bf(v.x) | ((unsigned int)f2bf(v.y) << 16);
            unsigned int p1 = (unsigned int)f2bf(v.z) | ((unsigned int)f2bf(v.w) << 16);
            *(unsigned int*)&Ab[r][half*64 + j*4]     = p0;
            *(unsigned int*)&Ab[r][half*64 + j*4 + 2] = p1;
        }
    }

    const int w  = tid >> 6, l = tid & 63;
    const int lr = l & 15,  lg = l >> 4;

    for (int it = 0; it < 16; ++it) {
        const int n0 = it * 64;
        __syncthreads();   // Wb/Cb safe to overwrite (prior readers done)
        {   // stage W: 4 threads per row, 32 floats each
            const int r = tid >> 2, q = tid & 3;
            const int g = n0 + r;
            const float* srcw = (g < 512) ? (w_ih_f + (long)g * 128)
                                          : (w_ih_b + (long)(g - 512) * 128);
            const float4* s4 = (const float4*)(srcw + q * 32);
            #pragma unroll
            for (int j = 0; j < 8; ++j) {
                float4 v = s4[j];
                unsigned int p0 = (unsigned int)f2bf(v.x) | ((unsigned int)f2bf(v.y) << 16);
                unsigned int p1 = (unsigned int)f2bf(v.z) | ((unsigned int)f2bf(v.w) << 16);
                *(unsigned int*)&Wb[r][q*32 + j*4]     = p0;
                *(unsigned int*)&Wb[r][q*32 + j*4 + 2] = p1;
            }
        }
        __syncthreads();

        f32x4 acc[2][4];
        #pragma unroll
        for (int a = 0; a < 2; ++a)
            #pragma unroll
            for (int c = 0; c < 4; ++c)
                acc[a][c] = (f32x4){0.f, 0.f, 0.f, 0.f};

        #pragma unroll
        for (int kk = 0; kk < 4; ++kk) {
            const int kb = kk * 32 + lg * 8;   // consistent A/B k-mapping
            short8 af[2], bfr[4];
            #pragma unroll
            for (int mt2 = 0; mt2 < 2; ++mt2)
                af[mt2] = *(const short8*)&Ab[w*32 + mt2*16 + lr][kb];
            #pragma unroll
            for (int nt2 = 0; nt2 < 4; ++nt2)
                bfr[nt2] = *(const short8*)&Wb[nt2*16 + lr][kb];
            #pragma unroll
            for (int mt2 = 0; mt2 < 2; ++mt2)
                #pragma unroll
                for (int nt2 = 0; nt2 < 4; ++nt2)
                    acc[mt2][nt2] = __builtin_amdgcn_mfma_f32_16x16x32_bf16(
                        af[mt2], bfr[nt2], acc[mt2][nt2], 0, 0, 0);
        }

        // write C fragments (+bias) into LDS transpose buffer
        #pragma unroll
        for (int nt2 = 0; nt2 < 4; ++nt2) {
            const int gc = n0 + nt2*16 + lr;
            const float bv = (gc < 512) ? (b_ih_f[gc] + b_hh_f[gc])
                                        : (b_ih_b[gc-512] + b_hh_b[gc-512]);
            #pragma unroll
            for (int mt2 = 0; mt2 < 2; ++mt2) {
                #pragma unroll
                for (int r = 0; r < 4; ++r) {
                    const int lrow = w*32 + mt2*16 + lg*4 + r;   // 0..127
                    Cb[lrow][nt2*16 + lr] = f2bf(acc[mt2][nt2][r] + bv);
                }
            }
        }
        __syncthreads();

        // coalesced store: thread (rr,hf) stores 32 bf16 = 4 x 16B
        {
            const int rr = tid >> 1, hf = tid & 1;
            const int grow = m0 + rr;
            long dst;
            if (n0 < 512) {
                dst = (long)grow * 512 + n0 + hf*32;
            } else {
                const int tt = grow >> 7, bb = grow & 127;
                dst = 33554432L + (long)((511 - tt) * 128 + bb) * 512 + (n0 - 512) + hf*32;
            }
            const unsigned short* srcC = &Cb[rr][hf*32];
            unsigned short* dp = xp + dst;
            #pragma unroll
            for (int j = 0; j < 4; ++j)
                *(short8*)(dp + j*8) = *(const short8*)(srcC + j*8);
        }
    }
}

// ---------------------------------------------------------------------------
// Kernel 2: LSTM recurrence. Grid 256 = (dir,b); 256 threads (4 waves), all
// CUs busy. launch_bounds(256,2) caps unified VGPRs at 256 so the 128 weight
// regs live in ARCH VGPRs (no accvgpr round-trip).
// Weight pairing (k, k+64): lane l owns units l and l+64; hpi packs
// (h[l], h[l+64]) directly. Gate LDS glx[unit][i,g,f,o]: one ds_write_b64 +
// one barrier + two ds_read_b128 per step (parity double-buffered).
// 4-way split accumulators shorten the fdot2 dep chain.
// ---------------------------------------------------------------------------
__global__ __launch_bounds__(256, 2) void lstm_rec(
    const unsigned short* __restrict__ xp,
    const float* __restrict__ w_hh_f, const float* __restrict__ w_hh_b,
    unsigned short* __restrict__ hbuf)
{
    const int tid = threadIdx.x;
    const int dir = blockIdx.x >> 7, b = blockIdx.x & 127;
    const float* whh = dir ? w_hh_b : w_hh_f;

    // rows owned: r1 = tid (i-gate rows 0..127 or f-gate rows 128..255),
    //             r2 = tid + 256 (g or o). Pairs are cols (j, j+64).
    h2 w1p[64], w2p[64];
    #pragma unroll
    for (int jj = 0; jj < 16; ++jj) {
        float4 a = *(const float4*)(whh + (long)tid * 128 + jj*4);
        float4 c = *(const float4*)(whh + (long)tid * 128 + 64 + jj*4);
        w1p[jj*4+0] = __builtin_amdgcn_cvt_pkrtz(a.x, c.x);
        w1p[jj*4+1] = __builtin_amdgcn_cvt_pkrtz(a.y, c.y);
        w1p[jj*4+2] = __builtin_amdgcn_cvt_pkrtz(a.z, c.z);
        w1p[jj*4+3] = __builtin_amdgcn_cvt_pkrtz(a.w, c.w);
    }
    #pragma unroll
    for (int jj = 0; jj < 16; ++jj) {
        float4 a = *(const float4*)(whh + (long)(tid + 256) * 128 + jj*4);
        float4 c = *(const float4*)(whh + (long)(tid + 256) * 128 + 64 + jj*4);
        w2p[jj*4+0] = __builtin_amdgcn_cvt_pkrtz(a.x, c.x);
        w2p[jj*4+1] = __builtin_amdgcn_cvt_pkrtz(a.y, c.y);
        w2p[jj*4+2] = __builtin_amdgcn_cvt_pkrtz(a.z, c.z);
        w2p[jj*4+3] = __builtin_amdgcn_cvt_pkrtz(a.w, c.w);
    }

    __shared__ float glx[2][128][4];   // [parity][unit][i,g,f,o]

    const int l    = tid & 63;
    const int u    = tid & 127;        // unit this thread's gate rows map to
    const int half = tid >> 7;         // 0: rows (i,g); 1: rows (f,o)

    float cv0 = 0.f, cv1 = 0.f;        // c[l], c[l+64] (redundant copy per wave)
    int hpi = 0;                       // packed (h[l], h[l+64]) f16
    const unsigned short* xpd = xp + (long)dir * 33554432L;

    unsigned short nxa = xpd[((long)0 * 128 + b) * 512 + tid];
    unsigned short nxb = xpd[((long)0 * 128 + b) * 512 + tid + 256];

    for (int t = 0; t < 512; ++t) {
        const int p = t & 1;
        const float xpv1 = bf2f(nxa);
        const float xpv2 = bf2f(nxb);
        if (t < 511) {   // prefetch next step, hidden under the dot loop
            const unsigned short* nr = xpd + ((long)(t+1) * 128 + b) * 512;
            nxa = nr[tid];
            nxb = nr[tid + 256];
        }

        float a1a = 0.f, a1b = 0.f, a2a = 0.f, a2b = 0.f;
        #pragma unroll
        for (int j = 0; j < 64; j += 2) {
            const h2 hj0 = i2h2(__builtin_amdgcn_readlane(hpi, j));
            const h2 hj1 = i2h2(__builtin_amdgcn_readlane(hpi, j + 1));
            a1a = dot2acc(w1p[j],     hj0, a1a);
            a2a = dot2acc(w2p[j],     hj0, a2a);
            a1b = dot2acc(w1p[j + 1], hj1, a1b);
            a2b = dot2acc(w2p[j + 1], hj1, a2b);
        }
        const float g1 = a1a + a1b + xpv1;   // i[u] (half0) or f[u] (half1)
        const float g2 = a2a + a2b + xpv2;   // g[u] (half0) or o[u] (half1)

        *(float2*)&glx[p][u][half * 2] = make_float2(g1, g2);
        __syncthreads();   // parity buffering makes one barrier/step safe

        const float4 q0 = *(const float4*)&glx[p][l][0];        // i,g,f,o @ unit l
        const float4 q1 = *(const float4*)&glx[p][l + 64][0];   // i,g,f,o @ unit l+64
        cv0 = sigf(q0.z) * cv0 + sigf(q0.x) * tanhf_(q0.y);
        cv1 = sigf(q1.z) * cv1 + sigf(q1.x) * tanhf_(q1.y);
        const float h0 = sigf(q0.w) * tanhf_(cv0);
        const float h1 = sigf(q1.w) * tanhf_(cv1);
        hpi = h22i(__builtin_amdgcn_cvt_pkrtz(h0, h1));

        if (tid < 64) {   // wave 0 stores h (units l and l+64)
            const int tt = dir ? (511 - t) : t;
            unsigned short* hd = hbuf + ((long)b * 512 + tt) * 256 + dir * 128;
            hd[l]      = f2bf(h0);
            hd[l + 64] = f2bf(h1);
        }
    }
}

// ---------------------------------------------------------------------------
// Kernel 3: emissions via MFMA. M=128 rows/block (grid 512), N=32 (17 used),
// K=256. w_emit staged in zero-padded bf16 fragments, h read direct global.
// ---------------------------------------------------------------------------
__global__ __launch_bounds__(256) void emission(
    const unsigned short* __restrict__ hbuf, const float* __restrict__ w_emit,
    const float* __restrict__ b_emit, float* __restrict__ em)
{
    const int tid = threadIdx.x, w = tid >> 6, l = tid & 63;
    const int lr = l & 15, lg = l >> 4;
    const int m0 = blockIdx.x * 128;

    // B fragments: 2 n-tiles x 8 k-frags, cols >= 17 zero
    short8 bf[2][8];
    #pragma unroll
    for (int nt = 0; nt < 2; ++nt) {
        const int col = nt*16 + lr;
        #pragma unroll
        for (int kk = 0; kk < 8; ++kk) {
            short8 v = (short8){0,0,0,0,0,0,0,0};
            if (col < 17) {
                const float* s = w_emit + (long)col * 256 + kk*32 + lg*8;
                const float4 a = *(const float4*)s;
                const float4 c = *(const float4*)(s + 4);
                v[0] = (short)f2bf(a.x); v[1] = (short)f2bf(a.y);
                v[2] = (short)f2bf(a.z); v[3] = (short)f2bf(a.w);
                v[4] = (short)f2bf(c.x); v[5] = (short)f2bf(c.y);
                v[6] = (short)f2bf(c.z); v[7] = (short)f2bf(c.w);
            }
            bf[nt][kk] = v;
        }
    }

    f32x4 acc[2][2];
    #pragma unroll
    for (int a = 0; a < 2; ++a)
        #pragma unroll
        for (int c = 0; c < 2; ++c)
            acc[a][c] = (f32x4){0.f, 0.f, 0.f, 0.f};

    #pragma unroll
    for (int kk = 0; kk < 8; ++kk) {
        short8 af[2];
        #pragma unroll
        for (int mt = 0; mt < 2; ++mt) {
            const long row = m0 + w*32 + mt*16 + lr;
            af[mt] = *(const short8*)(hbuf + row * 256 + kk*32 + lg*8);
        }
        #pragma unroll
        for (int mt = 0; mt < 2; ++mt)
            #pragma unroll
            for (int nt = 0; nt < 2; ++nt)
                acc[mt][nt] = __builtin_amdgcn_mfma_f32_16x16x32_bf16(
                    af[mt], bf[nt][kk], acc[mt][nt], 0, 0, 0);
    }

    #pragma unroll
    for (int mt = 0; mt < 2; ++mt)
        #pragma unroll
        for (int nt = 0; nt < 2; ++nt) {
            const int col = nt*16 + lr;
            if (col < 17) {
                const float bb = b_emit[col];
                #pragma unroll
                for (int r = 0; r < 4; ++r) {
                    const long row = m0 + w*32 + mt*16 + lg*4 + r;
                    em[row * 17 + col] = acc[mt][nt][r] + bb;
                }
            }
        }
}

// ---------------------------------------------------------------------------
// Kernel 4: CRF per batch element. Linear-domain forward, renorm every 4
// steps (worst-case growth e^76 < f32 max).
// ---------------------------------------------------------------------------
__global__ __launch_bounds__(64) void crf(
    const float* __restrict__ em, const int* __restrict__ tags,
    const float* __restrict__ start_t, const float* __restrict__ end_t,
    const float* __restrict__ trans, float* __restrict__ llh)
{
    const int b = blockIdx.x, l = threadIdx.x;
    const int* tg = tags + b * 512;
    const float* emb_ = em + (long)b * 512 * 17;

    // ---- numerator (gold path score), all 64 lanes ----
    float sc = 0.f;
    #pragma unroll
    for (int it = 0; it < 8; ++it) {
        const int t = it * 64 + l;
        const int cur = tg[t];
        float e = emb_[t * 17 + cur];
        float tr = (t > 0) ? trans[tg[t-1] * 17 + cur] : 0.f;
        sc += e + tr;
    }
    #pragma unroll
    for (int m = 32; m >= 1; m >>= 1) sc += __shfl_xor(sc, m, 64);

    // ---- denominator: linear-domain forward, periodic renorm ----
    const bool act = (l < 17);
    const int j = act ? l : 16;

    float eT[17];
    #pragma unroll
    for (int i = 0; i < 17; ++i) eT[i] = __expf(trans[i * 17 + j]);

    float v0 = act ? (start_t[j] + emb_[j]) : -1e30f;
    float m0 = v0;
    #pragma unroll
    for (int m = 32; m >= 1; m >>= 1) m0 = fmaxf(m0, __shfl_xor(m0, m, 64));
    float al = act ? __expf(v0 - m0) : 0.f;
    float accl = m0;   // accumulated natural-log scale

    float em_next = emb_[17 + j];
    for (int t = 1; t < 512; ++t) {
        const float emv = em_next;
        if (t + 1 < 512) em_next = emb_[(t + 1) * 17 + j];
        float s = 0.f;
        #pragma unroll
        for (int i = 0; i < 17; ++i) {
            const float ai = __int_as_float(
                __builtin_amdgcn_readlane(__float_as_int(al), i));
            s = fmaf(ai, eT[i], s);
        }
        al = act ? s * __expf(emv) : 0.f;
        if ((t & 3) == 0) {   // renorm every 4 steps
            float mx = al;
            #pragma unroll
            for (int m = 32; m >= 1; m >>= 1) mx = fmaxf(mx, __shfl_xor(mx, m, 64));
            al = al * __builtin_amdgcn_rcpf(mx);
            accl += __logf(mx);
        }
    }
    float fin = act ? al * __expf(end_t[j]) : 0.f;
    #pragma unroll
    for (int m = 32; m >= 1; m >>= 1) fin += __shfl_xor(fin, m, 64);
    const float logZ = __logf(fin) + accl;

    if (l == 0) {
        sc += start_t[tg[0]] + end_t[tg[511]];
        llh[b] = sc - logZ;
    }
}

// ---------------------------------------------------------------------------
// Kernel 5: nll = -mean(llh)
// ---------------------------------------------------------------------------
__global__ __launch_bounds__(64) void finalize(
    const float* __restrict__ llh, float* __restrict__ out)
{
    const int l = threadIdx.x;
    float s = llh[l] + llh[l + 64];
    #pragma unroll
    for (int m = 32; m >= 1; m >>= 1) s += __shfl_xor(s, m, 64);
    if (l == 0) out[0] = -s * (1.f / 128.f);
}

// ---------------------------------------------------------------------------
extern "C" void kernel_launch(void* const* d_in, const int* in_sizes, int n_in,
                              void* d_out, int out_size, void* d_ws, size_t ws_size,
                              hipStream_t stream) {
    (void)in_sizes; (void)n_in; (void)out_size; (void)ws_size;
    const int*   ids    = (const int*)d_in[0];
    const int*   tags   = (const int*)d_in[1];
    // d_in[2] = mask: all-ones by construction, ignored
    const float* emb    = (const float*)d_in[3];
    const float* w_ih_f = (const float*)d_in[4];
    const float* w_hh_f = (const float*)d_in[5];
    const float* b_ih_f = (const float*)d_in[6];
    const float* b_hh_f = (const float*)d_in[7];
    const float* w_ih_b = (const float*)d_in[8];
    const float* w_hh_b = (const float*)d_in[9];
    const float* b_ih_b = (const float*)d_in[10];
    const float* b_hh_b = (const float*)d_in[11];
    const float* w_emit = (const float*)d_in[12];
    const float* b_emit = (const float*)d_in[13];
    const float* st     = (const float*)d_in[14];
    const float* en     = (const float*)d_in[15];
    const float* tr     = (const float*)d_in[16];

    char* ws = (char*)d_ws;
    unsigned short* xp   = (unsigned short*)(ws);                 // bf16 [2][65536][512] = 128 MiB
    unsigned short* hbuf = (unsigned short*)(ws + 134217728L);    // bf16 [128][512][256] = 32 MiB
    float*          em   = (float*)(ws + 167772160L);             // f32  [65536][17]
    float*          llh  = (float*)(ws + 172228608L);             // f32  [128]
    float*          out  = (float*)d_out;

    xp_gemm<<<dim3(512), dim3(256), 0, stream>>>(ids, emb, w_ih_f, w_ih_b,
                                                 b_ih_f, b_hh_f, b_ih_b, b_hh_b, xp);
    lstm_rec<<<dim3(256), dim3(256), 0, stream>>>(xp, w_hh_f, w_hh_b, hbuf);
    emission<<<dim3(512), dim3(256), 0, stream>>>(hbuf, w_emit, b_emit, em);
    crf<<<dim3(128), dim3(64), 0, stream>>>(em, tags, st, en, tr, llh);
    finalize<<<dim3(1), dim3(64), 0, stream>>>(llh, out);
}